// Round 11
// baseline (1577.611 us; speedup 1.0000x reference)
//
#include <hip/hip_runtime.h>
#include <hip/hip_bf16.h>
#include <stdint.h>

#define M_TOTAL 8192
#define K_TOTAL 4096
#define N_TOTAL 16384
#define BM 256
#define BN 256
#define BK 32
#define KT2 (K_TOTAL / BK)             // 128 K-tiles of 32
#define TILE_B 16384                   // packed bytes per 256-row block per K-tile (per operand)
#define BUF_S 16384                    // LDS buffer: B only, 16KB
#define NBUF 4

typedef __bf16 bf16x8 __attribute__((ext_vector_type(8)));
typedef float f32x4 __attribute__((ext_vector_type(4)));
typedef unsigned short u16;
typedef u16 u16x8 __attribute__((ext_vector_type(8)));

static __device__ __forceinline__ u16 f2bf(float f) {
    unsigned int u = __builtin_bit_cast(unsigned int, f);
    u = (u + 0x7fffu + ((u >> 16) & 1u)) >> 16;   // RNE
    return (u16)u;
}

static __device__ __forceinline__ void async16(const void* g, void* l) {
    __builtin_amdgcn_global_load_lds((const __attribute__((address_space(1))) unsigned int*)g,
                                     (__attribute__((address_space(3))) unsigned int*)l,
                                     16, 0, 0);
}

// ---------------- packing kernels (unchanged layout) ----------------
// Packed layout per 256-row block (2MB): [kt 0..127][f 0..15][lane 0..63][16B]
// element (row, k): f=(row>>4)&15, lane=(row&15)|(((k>>3)&3)<<4), byte=(k&7)*2.
// A-frag (16 rows x 32 k) = 1KB = one global_load_dwordx4 at base+lane*16.

__global__ __launch_bounds__(256) void cvt_x_pack(const float* __restrict__ x, u16* __restrict__ xb) {
    long long j = (long long)blockIdx.x * 256 + threadIdx.x;
    int mt = (int)(j >> 17);           // 131072 threads per 256-row block
    int j2 = (int)(j & 131071);
    int kt = j2 >> 10;
    int f  = (j2 >> 6) & 15;
    int l  = j2 & 63;
    int r  = mt * 256 + f * 16 + (l & 15);
    int k0 = kt * 32 + ((l >> 4) << 3);
    const float4* s = reinterpret_cast<const float4*>(x + (size_t)r * K_TOTAL + k0);
    float4 a = s[0], b = s[1];
    u16x8 v;
    v[0] = f2bf(a.x); v[1] = f2bf(a.y); v[2] = f2bf(a.z); v[3] = f2bf(a.w);
    v[4] = f2bf(b.x); v[5] = f2bf(b.y); v[6] = f2bf(b.z); v[7] = f2bf(b.w);
    *reinterpret_cast<u16x8*>(xb + j * 8) = v;
}

__global__ __launch_bounds__(256) void cvt_w_pack(const int* __restrict__ w, u16* __restrict__ wb) {
    long long j = (long long)blockIdx.x * 256 + threadIdx.x;
    int nt = (int)(j >> 17);
    int j2 = (int)(j & 131071);
    int kt = j2 >> 10;
    int f  = (j2 >> 6) & 15;
    int l  = j2 & 63;
    int r  = nt * 256 + f * 16 + (l & 15);
    int k0 = kt * 32 + ((l >> 4) << 3);
    const int4* s = reinterpret_cast<const int4*>(w + (size_t)r * K_TOTAL + k0);
    int4 a = s[0], b = s[1];
    u16x8 v;
    v[0] = f2bf((float)a.x); v[1] = f2bf((float)a.y); v[2] = f2bf((float)a.z); v[3] = f2bf((float)a.w);
    v[4] = f2bf((float)b.x); v[5] = f2bf((float)b.y); v[6] = f2bf((float)b.z); v[7] = f2bf((float)b.w);
    *reinterpret_cast<u16x8*>(wb + j * 8) = v;
}

// ---------------- GEMM: A direct global->reg, B via LDS ----------------
// Window t (frag set s = t&1): STG_B(t+3 -> buf (t+3)&3) ; 8 global A-frag
// loads of tile t+1 -> afr[~s] (vmcnt, compiler-counted, 1 window of flight);
// 4 ds_read B-frags of tile t+1 -> bfr[~s]; 32 MFMA on set s; lgkm0;
// vmcnt(18) certifies B(t+2) staged (issued @t-1; newer = A(t):8 @t-1 +
// stgB(t+3):2 + A(t+1):8 @t = 18); s_barrier.
// LDS traffic/window/CU: 32KB reads + 16KB stage-writes (vs 96+32 before) —
// A's 4x wave-duplication now hits L1, unique 16KB/window from L2/L3.

#define BAR()    { asm volatile("" ::: "memory"); __builtin_amdgcn_s_barrier(); asm volatile("" ::: "memory"); }
#define LGKM0()  asm volatile("s_waitcnt lgkmcnt(0)" ::: "memory")
#define VMC18()  asm volatile("s_waitcnt vmcnt(18)" ::: "memory")
#define VMC16()  asm volatile("s_waitcnt vmcnt(16)" ::: "memory")
#define VMC10()  asm volatile("s_waitcnt vmcnt(10)" ::: "memory")
#define PRIO1()  __builtin_amdgcn_s_setprio(1)
#define PRIO0()  __builtin_amdgcn_s_setprio(0)
#define SCHEDB() __builtin_amdgcn_sched_barrier(0)

#define STG_B(tabs, buf) { \
    async16(bS + (size_t)(tabs)*TILE_B + tid*16,        ldsc + (buf)*BUF_S + tid*16); \
    async16(bS + (size_t)(tabs)*TILE_B + 8192 + tid*16, ldsc + (buf)*BUF_S + 8192 + tid*16); }

#define GLB_A0(tabs) { const char* aW = aF + (size_t)(tabs)*TILE_B; \
    _Pragma("unroll") for (int mi = 0; mi < 8; ++mi) \
        afr0[mi] = *(const bf16x8*)(aW + mi * 1024); }

#define GLB_A1(tabs) { const char* aW = aF + (size_t)(tabs)*TILE_B; \
    _Pragma("unroll") for (int mi = 0; mi < 8; ++mi) \
        afr1[mi] = *(const bf16x8*)(aW + mi * 1024); }

#define DS_B0(buf) { _Pragma("unroll") for (int ni = 0; ni < 4; ++ni) \
    bfr0[ni] = *(const bf16x8*)(bRd + (buf)*BUF_S + ni * 1024); }

#define DS_B1(buf) { _Pragma("unroll") for (int ni = 0; ni < 4; ++ni) \
    bfr1[ni] = *(const bf16x8*)(bRd + (buf)*BUF_S + ni * 1024); }

#define MMA0() { PRIO1(); \
    _Pragma("unroll") for (int mi = 0; mi < 8; ++mi) { _Pragma("unroll") \
        for (int ni = 0; ni < 4; ++ni) \
            acc[mi][ni] = __builtin_amdgcn_mfma_f32_16x16x32_bf16(afr0[mi], bfr0[ni], acc[mi][ni], 0, 0, 0); } \
    PRIO0(); }

#define MMA1() { PRIO1(); \
    _Pragma("unroll") for (int mi = 0; mi < 8; ++mi) { _Pragma("unroll") \
        for (int ni = 0; ni < 4; ++ni) \
            acc[mi][ni] = __builtin_amdgcn_mfma_f32_16x16x32_bf16(afr1[mi], bfr1[ni], acc[mi][ni], 0, 0, 0); } \
    PRIO0(); }

__global__ __launch_bounds__(512, 2) void gemm_kernel(const u16* __restrict__ A,
                                                      const u16* __restrict__ B,
                                                      const float* __restrict__ scale,
                                                      float* __restrict__ out) {
    extern __shared__ char ldsc[];
    const int tid  = threadIdx.x;
    const int lane = tid & 63;
    const int wave = tid >> 6;
    const int wm = wave >> 2;          // 0..1
    const int wn = wave & 3;           // 0..3

    // XCD-aware bijective swizzle (2048 blocks, 8 XCDs, 256-block chunks);
    // mt fastest within chunk -> 32 co-resident blocks/XCD share one B-panel.
    int orig = blockIdx.x;
    int swzid = (orig & 7) * 256 + (orig >> 3);
    int mt = swzid & 31;
    int nt = swzid >> 5;

    const char* aS = (const char*)A + (size_t)mt * (KT2 * TILE_B);
    const char* bS = (const char*)B + (size_t)nt * (KT2 * TILE_B);

    // per-thread A base: wave wm's frags are f = wm*8 + mi
    const char* aF = aS + wm * 8192 + lane * 16;
    // B LDS read base: wave wn covers f = wn*4 + ni
    const char* bRd = ldsc + wn * 4096 + lane * 16;

    f32x4 acc[8][4];
    #pragma unroll
    for (int mi = 0; mi < 8; ++mi)
        #pragma unroll
        for (int ni = 0; ni < 4; ++ni)
            acc[mi][ni] = (f32x4){0.f, 0.f, 0.f, 0.f};

    bf16x8 afr0[8], bfr0[4], afr1[8], bfr1[4];

    // prologue: stage B(0,1,2)->bufs 0,1,2 (6 loads); A(0)->set0 (8 loads);
    // VMC10 certifies B(0),B(1) (leaves B(2):2 + A(0):8 in flight); barrier;
    // read B(0) frags.
    STG_B(0, 0); STG_B(1, 1); STG_B(2, 2);
    GLB_A0(0);
    VMC10();
    BAR();
    DS_B0(0);

    // windows 0..123, unroll x4 (buf rotation period 4, frag sets period 2)
    for (int T = 0; T < 124; T += 4) {
        // w=T (set0): stg B(T+3)->buf3, A(T+1)->set1, dsB(T+1)<-buf1
        STG_B(T + 3, 3);
        GLB_A1(T + 1);
        DS_B1(1);
        SCHEDB();
        MMA0();
        SCHEDB();
        LGKM0(); VMC18(); BAR();
        // w=T+1 (set1): stg B(T+4)->buf0, A(T+2)->set0, dsB(T+2)<-buf2
        STG_B(T + 4, 0);
        GLB_A0(T + 2);
        DS_B0(2);
        SCHEDB();
        MMA1();
        SCHEDB();
        LGKM0(); VMC18(); BAR();
        // w=T+2 (set0): stg B(T+5)->buf1, A(T+3)->set1, dsB(T+3)<-buf3
        STG_B(T + 5, 1);
        GLB_A1(T + 3);
        DS_B1(3);
        SCHEDB();
        MMA0();
        SCHEDB();
        LGKM0(); VMC18(); BAR();
        // w=T+3 (set1): stg B(T+6)->buf2, A(T+4)->set0, dsB(T+4)<-buf0
        STG_B(T + 6, 2);
        GLB_A0(T + 4);
        DS_B0(0);
        SCHEDB();
        MMA1();
        SCHEDB();
        LGKM0(); VMC18(); BAR();
    }
    // window 124 (set0): stg B(127)->buf3, A(125)->set1, dsB(125)<-buf1
    STG_B(127, 3);
    GLB_A1(125);
    DS_B1(1);
    SCHEDB();
    MMA0();
    SCHEDB();
    LGKM0(); VMC18(); BAR();
    // window 125 (set1): A(126)->set0, dsB(126)<-buf2
    GLB_A0(126);
    DS_B0(2);
    SCHEDB();
    MMA1();
    SCHEDB();
    LGKM0(); VMC16(); BAR();       // certify B(127) (newer = A(125):8 + A(126):8)
    // window 126 (set0): A(127)->set1, dsB(127)<-buf3
    GLB_A1(127);
    DS_B1(3);
    SCHEDB();
    MMA0();
    SCHEDB();
    // window 127 (set1): MFMA only (compiler inserts vmcnt/lgkm for set1)
    MMA1();

    // epilogue: D row=(lane>>4)*4+j, col=lane&15; scale per output col
    int m0 = mt * BM, n0 = nt * BN;
    int col0 = n0 + wn * 64 + (lane & 15);
    int row0 = m0 + wm * 128 + ((lane >> 4) << 2);
    #pragma unroll
    for (int ni = 0; ni < 4; ++ni) {
        float sc = scale[col0 + ni * 16];
        #pragma unroll
        for (int mi = 0; mi < 8; ++mi) {
            #pragma unroll
            for (int j = 0; j < 4; ++j) {
                out[(size_t)(row0 + mi * 16 + j) * N_TOTAL + (col0 + ni * 16)] = acc[mi][ni][j] * sc;
            }
        }
    }
}

// ---------------- fallback ----------------

__global__ __launch_bounds__(256) void naive_kernel(const float* __restrict__ x, const int* __restrict__ w,
                                                    const float* __restrict__ scale, float* __restrict__ out) {
    int n = blockIdx.x * 256 + threadIdx.x;
    int m = blockIdx.y;
    const float* xr = x + (size_t)m * K_TOTAL;
    const int*   wr = w + (size_t)n * K_TOTAL;
    float acc = 0.f;
    for (int k = 0; k < K_TOTAL; k += 4) {
        float4 xv = *(const float4*)(xr + k);
        int4   wv = *(const int4*)(wr + k);
        acc += xv.x * (float)wv.x + xv.y * (float)wv.y + xv.z * (float)wv.z + xv.w * (float)wv.w;
    }
    out[(size_t)m * N_TOTAL + n] = acc * scale[n];
}

extern "C" void kernel_launch(void* const* d_in, const int* in_sizes, int n_in,
                              void* d_out, int out_size, void* d_ws, size_t ws_size,
                              hipStream_t stream) {
    const float* x     = (const float*)d_in[0];
    const int*   w     = (const int*)d_in[1];
    const float* scale = (const float*)d_in[2];
    float* out = (float*)d_out;

    const size_t xb_bytes = (size_t)M_TOTAL * K_TOTAL * 2;
    const size_t wb_bytes = (size_t)N_TOTAL * K_TOTAL * 2;

    if (ws_size >= xb_bytes + wb_bytes) {
        u16* xb = (u16*)d_ws;
        u16* wb = (u16*)((char*)d_ws + xb_bytes);
        (void)hipFuncSetAttribute((const void*)gemm_kernel,
                                  hipFuncAttributeMaxDynamicSharedMemorySize, NBUF * BUF_S);
        cvt_x_pack<<<(M_TOTAL / 256) * (K_TOTAL / 8), 256, 0, stream>>>(x, xb);
        cvt_w_pack<<<(N_TOTAL / 256) * (K_TOTAL / 8), 256, 0, stream>>>(w, wb);
        gemm_kernel<<<(M_TOTAL / BM) * (N_TOTAL / BN), 512, NBUF * BUF_S, stream>>>(xb, wb, scale, out);
    } else {
        dim3 g(N_TOTAL / 256, M_TOTAL);
        naive_kernel<<<g, 256, 0, stream>>>(x, w, scale, out);
    }
}

// Round 12
// 1163.107 us; speedup vs baseline: 1.3564x; 1.3564x over previous
//
#include <hip/hip_runtime.h>
#include <hip/hip_bf16.h>
#include <stdint.h>

#define M_TOTAL 8192
#define K_TOTAL 4096
#define N_TOTAL 16384
#define BM 256
#define BN 256
#define BK 32
#define KT2 (K_TOTAL / BK)             // 128 K-tiles of 32
#define TILE_B 16384                   // packed bytes per 256-row block per K-tile (per operand)
#define BUF_S 32768                    // LDS buffer: A 16KB + B 16KB
#define NBUF 4

typedef __bf16 bf16x8 __attribute__((ext_vector_type(8)));
typedef float f32x4 __attribute__((ext_vector_type(4)));
typedef unsigned short u16;
typedef u16 u16x8 __attribute__((ext_vector_type(8)));

static __device__ __forceinline__ u16 f2bf(float f) {
    unsigned int u = __builtin_bit_cast(unsigned int, f);
    u = (u + 0x7fffu + ((u >> 16) & 1u)) >> 16;   // RNE
    return (u16)u;
}

static __device__ __forceinline__ void async16(const void* g, void* l) {
    __builtin_amdgcn_global_load_lds((const __attribute__((address_space(1))) unsigned int*)g,
                                     (__attribute__((address_space(3))) unsigned int*)l,
                                     16, 0, 0);
}

// ---------------- packing kernels ----------------
// Packed layout per 256-row block (2MB): [kt 0..127][f 0..15][lane 0..63][16B]
// element (row, k): f=(row>>4)&15, lane=(row&15)|(((k>>3)&3)<<4), byte=(k&7)*2.
// Frag ds_read = uniform base + lane*16: stride-1, conflict-free, zero VALU.

__global__ __launch_bounds__(256) void cvt_x_pack(const float* __restrict__ x, u16* __restrict__ xb) {
    long long j = (long long)blockIdx.x * 256 + threadIdx.x;
    int mt = (int)(j >> 17);           // 131072 threads per 256-row block
    int j2 = (int)(j & 131071);
    int kt = j2 >> 10;
    int f  = (j2 >> 6) & 15;
    int l  = j2 & 63;
    int r  = mt * 256 + f * 16 + (l & 15);
    int k0 = kt * 32 + ((l >> 4) << 3);
    const float4* s = reinterpret_cast<const float4*>(x + (size_t)r * K_TOTAL + k0);
    float4 a = s[0], b = s[1];
    u16x8 v;
    v[0] = f2bf(a.x); v[1] = f2bf(a.y); v[2] = f2bf(a.z); v[3] = f2bf(a.w);
    v[4] = f2bf(b.x); v[5] = f2bf(b.y); v[6] = f2bf(b.z); v[7] = f2bf(b.w);
    *reinterpret_cast<u16x8*>(xb + j * 8) = v;
}

__global__ __launch_bounds__(256) void cvt_w_pack(const int* __restrict__ w, u16* __restrict__ wb) {
    long long j = (long long)blockIdx.x * 256 + threadIdx.x;
    int nt = (int)(j >> 17);
    int j2 = (int)(j & 131071);
    int kt = j2 >> 10;
    int f  = (j2 >> 6) & 15;
    int l  = j2 & 63;
    int r  = nt * 256 + f * 16 + (l & 15);
    int k0 = kt * 32 + ((l >> 4) << 3);
    const int4* s = reinterpret_cast<const int4*>(w + (size_t)r * K_TOTAL + k0);
    int4 a = s[0], b = s[1];
    u16x8 v;
    v[0] = f2bf((float)a.x); v[1] = f2bf((float)a.y); v[2] = f2bf((float)a.z); v[3] = f2bf((float)a.w);
    v[4] = f2bf((float)b.x); v[5] = f2bf((float)b.y); v[6] = f2bf((float)b.z); v[7] = f2bf((float)b.w);
    *reinterpret_cast<u16x8*>(wb + j * 8) = v;
}

// ---------------- GEMM: double frag sets + SGB 3:8 DS:MFMA interleave ----------------
// Window w (set s = w&1): STG(tile w+3 -> buf (w+3)&3); 12 ds_reads of tile
// w+1 -> set ~s; 32 MFMA on set s (loaded last window). One scheduling region
// per window; sched_group_barrier pins emission to {VMEM x4, then 4 x
// (DS_READ x3, MFMA x8)} so no wave ever issues a >4 ds_read burst (shallow
// per-wave LDS queue stalls issue -> rounds 4-9's serialization). Each
// read-triplet's ~36cyc LDS service hides under the next 8-MFMA matrix stall.
// Safety: tile w+1 certified by vmcnt(4)+bar at end of w-1 (stage(w+1) issued
// @w-2, newer stages = (w-1):4 -> wait<=4 drains it); staged buf (w+3)&3 last
// read at window w-2, lgkm0+bar twice before overwrite.

#define BAR()    { asm volatile("" ::: "memory"); __builtin_amdgcn_s_barrier(); asm volatile("" ::: "memory"); }
#define LGKM0()  asm volatile("s_waitcnt lgkmcnt(0)" ::: "memory")
#define VMC4()   asm volatile("s_waitcnt vmcnt(4)" ::: "memory")
#define VMC0()   asm volatile("s_waitcnt vmcnt(0)" ::: "memory")
#define PRIO1()  __builtin_amdgcn_s_setprio(1)
#define PRIO0()  __builtin_amdgcn_s_setprio(0)
#define SCHEDB() __builtin_amdgcn_sched_barrier(0)

// emission pattern: 4 stage-loads first, then 3 ds_read : 8 mfma x4
#define SGB_FULL() { \
    __builtin_amdgcn_sched_group_barrier(0x020, 4, 0); \
    __builtin_amdgcn_sched_group_barrier(0x100, 3, 0); \
    __builtin_amdgcn_sched_group_barrier(0x008, 8, 0); \
    __builtin_amdgcn_sched_group_barrier(0x100, 3, 0); \
    __builtin_amdgcn_sched_group_barrier(0x008, 8, 0); \
    __builtin_amdgcn_sched_group_barrier(0x100, 3, 0); \
    __builtin_amdgcn_sched_group_barrier(0x008, 8, 0); \
    __builtin_amdgcn_sched_group_barrier(0x100, 3, 0); \
    __builtin_amdgcn_sched_group_barrier(0x008, 8, 0); }

#define SGB_NOSTG() { \
    __builtin_amdgcn_sched_group_barrier(0x100, 3, 0); \
    __builtin_amdgcn_sched_group_barrier(0x008, 8, 0); \
    __builtin_amdgcn_sched_group_barrier(0x100, 3, 0); \
    __builtin_amdgcn_sched_group_barrier(0x008, 8, 0); \
    __builtin_amdgcn_sched_group_barrier(0x100, 3, 0); \
    __builtin_amdgcn_sched_group_barrier(0x008, 8, 0); \
    __builtin_amdgcn_sched_group_barrier(0x100, 3, 0); \
    __builtin_amdgcn_sched_group_barrier(0x008, 8, 0); }

#define STG(ts, so) { \
    async16(aS + (size_t)(ts)*TILE_B + tid*16,        ldsc + (so) + tid*16); \
    async16(aS + (size_t)(ts)*TILE_B + 8192 + tid*16, ldsc + (so) + 8192 + tid*16); \
    async16(bS + (size_t)(ts)*TILE_B + tid*16,        ldsc + (so) + 16384 + tid*16); \
    async16(bS + (size_t)(ts)*TILE_B + 8192 + tid*16, ldsc + (so) + 24576 + tid*16); }

#define RDF0(bo) { \
    _Pragma("unroll") for (int ni = 0; ni < 4; ++ni) bfr0[ni] = *(const bf16x8*)(bRd + (bo) + ni * 1024); \
    _Pragma("unroll") for (int mi = 0; mi < 8; ++mi) afr0[mi] = *(const bf16x8*)(aRd + (bo) + mi * 1024); }

#define RDF1(bo) { \
    _Pragma("unroll") for (int ni = 0; ni < 4; ++ni) bfr1[ni] = *(const bf16x8*)(bRd + (bo) + ni * 1024); \
    _Pragma("unroll") for (int mi = 0; mi < 8; ++mi) afr1[mi] = *(const bf16x8*)(aRd + (bo) + mi * 1024); }

#define MMA0() { PRIO1(); \
    _Pragma("unroll") for (int mi = 0; mi < 8; ++mi) { _Pragma("unroll") \
        for (int ni = 0; ni < 4; ++ni) \
            acc[mi][ni] = __builtin_amdgcn_mfma_f32_16x16x32_bf16(afr0[mi], bfr0[ni], acc[mi][ni], 0, 0, 0); } \
    PRIO0(); }

#define MMA1() { PRIO1(); \
    _Pragma("unroll") for (int mi = 0; mi < 8; ++mi) { _Pragma("unroll") \
        for (int ni = 0; ni < 4; ++ni) \
            acc[mi][ni] = __builtin_amdgcn_mfma_f32_16x16x32_bf16(afr1[mi], bfr1[ni], acc[mi][ni], 0, 0, 0); } \
    PRIO0(); }

#define WIN(st, sb, rb, RDFx, MMAx) { \
    STG(st, sb); \
    RDFx(rb); \
    MMAx(); \
    SGB_FULL(); \
    LGKM0(); VMC4(); BAR(); SCHEDB(); }

__global__ __launch_bounds__(512, 2) void gemm_kernel(const u16* __restrict__ A,
                                                      const u16* __restrict__ B,
                                                      const float* __restrict__ scale,
                                                      float* __restrict__ out) {
    extern __shared__ char ldsc[];
    const int tid  = threadIdx.x;
    const int lane = tid & 63;
    const int wave = tid >> 6;
    const int wm = wave >> 2;          // 0..1
    const int wn = wave & 3;           // 0..3

    // XCD-aware bijective swizzle (2048 blocks, 8 XCDs, 256-block chunks);
    // mt fastest within chunk -> 32 co-resident blocks/XCD share one B-panel.
    int orig = blockIdx.x;
    int swzid = (orig & 7) * 256 + (orig >> 3);
    int mt = swzid & 31;
    int nt = swzid >> 5;

    const char* aS = (const char*)A + (size_t)mt * (KT2 * TILE_B);
    const char* bS = (const char*)B + (size_t)nt * (KT2 * TILE_B);

    // fragment read bases: stride-1 1KB wave reads (uniform base + lane*16)
    const char* aRd = ldsc + wm * 8192 + lane * 16;           // + bo + mi*1024
    const char* bRd = ldsc + 16384 + wn * 4096 + lane * 16;   // + bo + ni*1024

    f32x4 acc[8][4];
    #pragma unroll
    for (int mi = 0; mi < 8; ++mi)
        #pragma unroll
        for (int ni = 0; ni < 4; ++ni)
            acc[mi][ni] = (f32x4){0.f, 0.f, 0.f, 0.f};

    bf16x8 afr0[8], bfr0[4], afr1[8], bfr1[4];

    // prologue: stage tiles 0,1,2 -> bufs 0,1,2; VMC4 drains stages 0,1
    // (tiles 0 and 1 certified, stage2's 4 loads stay in flight); barrier;
    // read tile 0 -> set0 (fenced into its own region).
    STG(0, 0); STG(1, BUF_S); STG(2, 2 * BUF_S);
    VMC4();
    BAR();
    SCHEDB();
    RDF0(0);
    SCHEDB();

    // windows 0..123 (stage tiles 3..126; reads tiles 1..124)
    for (int T = 0; T < 124; T += 4) {
        WIN(T + 3, 3 * BUF_S, 1 * BUF_S, RDF1, MMA0);   // w=T:   mfma T, rd T+1
        WIN(T + 4, 0,         2 * BUF_S, RDF0, MMA1);   // w=T+1: mfma T+1, rd T+2
        WIN(T + 5, 1 * BUF_S, 3 * BUF_S, RDF1, MMA0);   // w=T+2: mfma T+2, rd T+3
        WIN(T + 6, 2 * BUF_S, 0,         RDF0, MMA1);   // w=T+3: mfma T+3, rd T+4
    }
    // w=124 (set0): stage tile 127 -> buf3; rd tile 125 <- buf1; mfma 124.
    // end VMC4 drains stage(126) -> tile 126 certified.
    WIN(127, 3 * BUF_S, 1 * BUF_S, RDF1, MMA0);
    // w=125 (set1): rd tile 126 <- buf2; mfma 125; VMC0 certifies tile 127.
    RDF0(2 * BUF_S);
    MMA1();
    SGB_NOSTG();
    LGKM0(); VMC0(); BAR(); SCHEDB();
    // w=126 (set0): rd tile 127 <- buf3; mfma 126.
    RDF1(3 * BUF_S);
    MMA0();
    SGB_NOSTG();
    LGKM0();
    // w=127 (set1): mfma 127.
    MMA1();

    // epilogue: D row=(lane>>4)*4+j, col=lane&15; scale per output col
    int m0 = mt * BM, n0 = nt * BN;
    int col0 = n0 + wn * 64 + (lane & 15);
    int row0 = m0 + wm * 128 + ((lane >> 4) << 2);
    #pragma unroll
    for (int ni = 0; ni < 4; ++ni) {
        float sc = scale[col0 + ni * 16];
        #pragma unroll
        for (int mi = 0; mi < 8; ++mi) {
            #pragma unroll
            for (int j = 0; j < 4; ++j) {
                out[(size_t)(row0 + mi * 16 + j) * N_TOTAL + (col0 + ni * 16)] = acc[mi][ni][j] * sc;
            }
        }
    }
}

// ---------------- fallback ----------------

__global__ __launch_bounds__(256) void naive_kernel(const float* __restrict__ x, const int* __restrict__ w,
                                                    const float* __restrict__ scale, float* __restrict__ out) {
    int n = blockIdx.x * 256 + threadIdx.x;
    int m = blockIdx.y;
    const float* xr = x + (size_t)m * K_TOTAL;
    const int*   wr = w + (size_t)n * K_TOTAL;
    float acc = 0.f;
    for (int k = 0; k < K_TOTAL; k += 4) {
        float4 xv = *(const float4*)(xr + k);
        int4   wv = *(const int4*)(wr + k);
        acc += xv.x * (float)wv.x + xv.y * (float)wv.y + xv.z * (float)wv.z + xv.w * (float)wv.w;
    }
    out[(size_t)m * N_TOTAL + n] = acc * scale[n];
}

extern "C" void kernel_launch(void* const* d_in, const int* in_sizes, int n_in,
                              void* d_out, int out_size, void* d_ws, size_t ws_size,
                              hipStream_t stream) {
    const float* x     = (const float*)d_in[0];
    const int*   w     = (const int*)d_in[1];
    const float* scale = (const float*)d_in[2];
    float* out = (float*)d_out;

    const size_t xb_bytes = (size_t)M_TOTAL * K_TOTAL * 2;
    const size_t wb_bytes = (size_t)N_TOTAL * K_TOTAL * 2;

    if (ws_size >= xb_bytes + wb_bytes) {
        u16* xb = (u16*)d_ws;
        u16* wb = (u16*)((char*)d_ws + xb_bytes);
        (void)hipFuncSetAttribute((const void*)gemm_kernel,
                                  hipFuncAttributeMaxDynamicSharedMemorySize, NBUF * BUF_S);
        cvt_x_pack<<<(M_TOTAL / 256) * (K_TOTAL / 8), 256, 0, stream>>>(x, xb);
        cvt_w_pack<<<(N_TOTAL / 256) * (K_TOTAL / 8), 256, 0, stream>>>(w, wb);
        gemm_kernel<<<(M_TOTAL / BM) * (N_TOTAL / BN), 512, NBUF * BUF_S, stream>>>(xb, wb, scale, out);
    } else {
        dim3 g(N_TOTAL / 256, M_TOTAL);
        naive_kernel<<<g, 256, 0, stream>>>(x, w, scale, out);
    }
}

// Round 13
// 765.812 us; speedup vs baseline: 2.0600x; 1.5188x over previous
//
#include <hip/hip_runtime.h>
#include <hip/hip_bf16.h>
#include <stdint.h>

#define M_TOTAL 8192
#define K_TOTAL 4096
#define N_TOTAL 16384
#define BM 256
#define BN 256
#define KT 64                          // 64 K-tiles of 64 (i8: one MFMA eats K=64)
#define TILE_B 16384                   // bytes per 256-row block per K-tile (256 x 64 x 1B)
#define BUF_S 32768                    // LDS buffer: A 16KB + B 16KB
#define NBUF 4

typedef int i32x4 __attribute__((ext_vector_type(4)));

static __device__ __forceinline__ void async16(const void* g, void* l) {
    __builtin_amdgcn_global_load_lds((const __attribute__((address_space(1))) unsigned int*)g,
                                     (__attribute__((address_space(3))) unsigned int*)l,
                                     16, 0, 0);
}

// ---------------- scale + packing kernels ----------------
// Packed i8 layout per 256-row block (1MB): [kt 0..63][f 0..15][lane 0..63][16B]
// element (row, k): f=(row>>4)&15, lane=(row&15)|(((k>>4)&3)<<4), byte=k&15.
// Matches mfma_i32_16x16x64_i8 operand: lane&15=row, lane>>4=k-chunk of 16
// consecutive elements (K/4 rule, same pattern as verified bf16 16x16x32).

__global__ __launch_bounds__(256) void rowmax_kernel(const float* __restrict__ x,
                                                     float* __restrict__ sx,
                                                     float* __restrict__ invx) {
    int row = blockIdx.x * 4 + (threadIdx.x >> 6);
    int lane = threadIdx.x & 63;
    const float4* p = reinterpret_cast<const float4*>(x + (size_t)row * K_TOTAL) + lane;
    float m = 0.f;
    #pragma unroll
    for (int i = 0; i < 16; ++i) {
        float4 v = p[i * 64];
        m = fmaxf(m, fmaxf(fmaxf(fabsf(v.x), fabsf(v.y)), fmaxf(fabsf(v.z), fabsf(v.w))));
    }
    #pragma unroll
    for (int off = 32; off; off >>= 1) m = fmaxf(m, __shfl_xor(m, off, 64));
    if (lane == 0) {
        m = fmaxf(m, 1e-20f);
        sx[row]   = m / 127.f;
        invx[row] = 127.f / m;
    }
}

__global__ __launch_bounds__(256) void cvt_x_pack(const float* __restrict__ x,
                                                  const float* __restrict__ invx,
                                                  char* __restrict__ xq) {
    size_t j = (size_t)blockIdx.x * 256 + threadIdx.x;   // 16 output bytes each
    int mt = (int)(j >> 16);           // 65536 threads per 256-row block
    int j2 = (int)(j & 65535);
    int kt = j2 >> 10;
    int f  = (j2 >> 6) & 15;
    int l  = j2 & 63;
    int r  = mt * 256 + f * 16 + (l & 15);
    int k0 = kt * 64 + ((l >> 4) << 4);
    float is = invx[r];
    const float4* s = reinterpret_cast<const float4*>(x + (size_t)r * K_TOTAL + k0);
    int q[16];
    #pragma unroll
    for (int v4 = 0; v4 < 4; ++v4) {
        float4 v = s[v4];
        q[v4 * 4 + 0] = (int)__builtin_rintf(v.x * is);
        q[v4 * 4 + 1] = (int)__builtin_rintf(v.y * is);
        q[v4 * 4 + 2] = (int)__builtin_rintf(v.z * is);
        q[v4 * 4 + 3] = (int)__builtin_rintf(v.w * is);
    }
    int4 d;
    d.x = (q[0]&0xff) | ((q[1]&0xff)<<8) | ((q[2]&0xff)<<16) | (q[3]<<24);
    d.y = (q[4]&0xff) | ((q[5]&0xff)<<8) | ((q[6]&0xff)<<16) | (q[7]<<24);
    d.z = (q[8]&0xff) | ((q[9]&0xff)<<8) | ((q[10]&0xff)<<16) | (q[11]<<24);
    d.w = (q[12]&0xff) | ((q[13]&0xff)<<8) | ((q[14]&0xff)<<16) | (q[15]<<24);
    *reinterpret_cast<int4*>(xq + j * 16) = d;
}

__global__ __launch_bounds__(256) void cvt_w_pack(const int* __restrict__ w,
                                                  char* __restrict__ wq) {
    size_t j = (size_t)blockIdx.x * 256 + threadIdx.x;
    int nt = (int)(j >> 16);
    int j2 = (int)(j & 65535);
    int kt = j2 >> 10;
    int f  = (j2 >> 6) & 15;
    int l  = j2 & 63;
    int r  = nt * 256 + f * 16 + (l & 15);
    int k0 = kt * 64 + ((l >> 4) << 4);
    const int4* s = reinterpret_cast<const int4*>(w + (size_t)r * K_TOTAL + k0);
    int4 v0 = s[0], v1 = s[1], v2 = s[2], v3 = s[3];
    int4 d;
    d.x = (v0.x&0xff) | ((v0.y&0xff)<<8) | ((v0.z&0xff)<<16) | (v0.w<<24);
    d.y = (v1.x&0xff) | ((v1.y&0xff)<<8) | ((v1.z&0xff)<<16) | (v1.w<<24);
    d.z = (v2.x&0xff) | ((v2.y&0xff)<<8) | ((v2.z&0xff)<<16) | (v2.w<<24);
    d.w = (v3.x&0xff) | ((v3.y&0xff)<<8) | ((v3.z&0xff)<<16) | (v3.w<<24);
    *reinterpret_cast<int4*>(wq + j * 16) = d;
}

// ---------------- GEMM: i8 MFMA, round-9 window structure, 64 windows ----------------
// Window w (set s = w&1): STG(tile w+3 -> buf (w+3)&3); 12 ds_reads of tile
// w+1 -> set ~s; 32 mfma_i32_16x16x64_i8 on set s; lgkm0; vmcnt(4); barrier.
// Identical per-window profile to the bf16 round-9 kernel (4 stages, 12
// ds_read_b128, 32 MFMA) but each window covers K=64 -> 64 windows not 128.
// Safety: stage(w+2) issued @w-1; newer loads at wait = stage(w+3):4 ->
// vmcnt(4) certifies tile w+2 (read at start of w+1). Staged buffer's last
// reader retired (lgkm0) two barriers before overwrite.

#define BAR()    { asm volatile("" ::: "memory"); __builtin_amdgcn_s_barrier(); asm volatile("" ::: "memory"); }
#define LGKM0()  asm volatile("s_waitcnt lgkmcnt(0)" ::: "memory")
#define VMC4()   asm volatile("s_waitcnt vmcnt(4)" ::: "memory")
#define VMC0()   asm volatile("s_waitcnt vmcnt(0)" ::: "memory")
#define PRIO1()  __builtin_amdgcn_s_setprio(1)
#define PRIO0()  __builtin_amdgcn_s_setprio(0)
#define SCHEDB() __builtin_amdgcn_sched_barrier(0)

#define STG(ts, so) { \
    async16(aS + (size_t)(ts)*TILE_B + tid*16,        ldsc + (so) + tid*16); \
    async16(aS + (size_t)(ts)*TILE_B + 8192 + tid*16, ldsc + (so) + 8192 + tid*16); \
    async16(bS + (size_t)(ts)*TILE_B + tid*16,        ldsc + (so) + 16384 + tid*16); \
    async16(bS + (size_t)(ts)*TILE_B + 8192 + tid*16, ldsc + (so) + 24576 + tid*16); }

#define RDF0(bo) { \
    _Pragma("unroll") for (int ni = 0; ni < 4; ++ni) bfr0[ni] = *(const i32x4*)(bRd + (bo) + ni * 1024); \
    _Pragma("unroll") for (int mi = 0; mi < 8; ++mi) afr0[mi] = *(const i32x4*)(aRd + (bo) + mi * 1024); }

#define RDF1(bo) { \
    _Pragma("unroll") for (int ni = 0; ni < 4; ++ni) bfr1[ni] = *(const i32x4*)(bRd + (bo) + ni * 1024); \
    _Pragma("unroll") for (int mi = 0; mi < 8; ++mi) afr1[mi] = *(const i32x4*)(aRd + (bo) + mi * 1024); }

#define MMA0() { PRIO1(); \
    _Pragma("unroll") for (int mi = 0; mi < 8; ++mi) { _Pragma("unroll") \
        for (int ni = 0; ni < 4; ++ni) \
            acc[mi][ni] = __builtin_amdgcn_mfma_i32_16x16x64_i8(afr0[mi], bfr0[ni], acc[mi][ni], 0, 0, 0); } \
    PRIO0(); }

#define MMA1() { PRIO1(); \
    _Pragma("unroll") for (int mi = 0; mi < 8; ++mi) { _Pragma("unroll") \
        for (int ni = 0; ni < 4; ++ni) \
            acc[mi][ni] = __builtin_amdgcn_mfma_i32_16x16x64_i8(afr1[mi], bfr1[ni], acc[mi][ni], 0, 0, 0); } \
    PRIO0(); }

#define WIN(st, sb, rb, RDFx, MMAx) { \
    STG(st, sb); \
    RDFx(rb); \
    SCHEDB(); \
    MMAx(); \
    SCHEDB(); \
    LGKM0(); VMC4(); BAR(); }

__global__ __launch_bounds__(512, 2) void gemm_kernel(const char* __restrict__ A,
                                                      const char* __restrict__ B,
                                                      const float* __restrict__ scale,
                                                      const float* __restrict__ sx,
                                                      float* __restrict__ out) {
    extern __shared__ char ldsc[];
    const int tid  = threadIdx.x;
    const int lane = tid & 63;
    const int wave = tid >> 6;
    const int wm = wave >> 2;          // 0..1
    const int wn = wave & 3;           // 0..3

    // XCD-aware bijective swizzle (2048 blocks, 8 XCDs, 256-block chunks);
    // mt fastest within chunk -> 32 co-resident blocks/XCD share one B-panel.
    int orig = blockIdx.x;
    int swzid = (orig & 7) * 256 + (orig >> 3);
    int mt = swzid & 31;
    int nt = swzid >> 5;

    const char* aS = A + (size_t)mt * (KT * TILE_B);
    const char* bS = B + (size_t)nt * (KT * TILE_B);

    // fragment read bases: stride-1 1KB wave reads (uniform base + lane*16)
    const char* aRd = ldsc + wm * 8192 + lane * 16;           // + bo + mi*1024
    const char* bRd = ldsc + 16384 + wn * 4096 + lane * 16;   // + bo + ni*1024

    i32x4 acc[8][4];
    #pragma unroll
    for (int mi = 0; mi < 8; ++mi)
        #pragma unroll
        for (int ni = 0; ni < 4; ++ni)
            acc[mi][ni] = (i32x4){0, 0, 0, 0};

    i32x4 afr0[8], bfr0[4], afr1[8], bfr1[4];

    // prologue: stage tiles 0,1,2 -> bufs 0,1,2; VMC4 drains stages 0,1
    // (tiles 0,1 certified; stage2's 4 loads stay in flight); barrier;
    // read tile 0 -> set0.
    STG(0, 0); STG(1, BUF_S); STG(2, 2 * BUF_S);
    VMC4();
    BAR();
    RDF0(0);
    LGKM0();

    // windows 0..59 (stage tiles 3..62), unroll x4 for static LDS offsets
    for (int T = 0; T < 60; T += 4) {
        WIN(T + 3, 3 * BUF_S, 1 * BUF_S, RDF1, MMA0);   // w=T:   mfma T,   rd T+1
        WIN(T + 4, 0,         2 * BUF_S, RDF0, MMA1);   // w=T+1: mfma T+1, rd T+2
        WIN(T + 5, 1 * BUF_S, 3 * BUF_S, RDF1, MMA0);   // w=T+2: mfma T+2, rd T+3
        WIN(T + 6, 2 * BUF_S, 0,         RDF0, MMA1);   // w=T+3: mfma T+3, rd T+4
    }
    // window 60 (set0): stage tile 63 -> buf3; rd tile 61 <- buf1; mfma 60.
    WIN(63, 3 * BUF_S, 1 * BUF_S, RDF1, MMA0);
    // window 61 (set1): rd tile 62 <- buf2; mfma 61; VMC0 certifies tile 63.
    RDF0(2 * BUF_S);
    SCHEDB();
    MMA1();
    SCHEDB();
    LGKM0(); VMC0(); BAR();
    // window 62 (set0): rd tile 63 <- buf3; mfma 62.
    RDF1(3 * BUF_S);
    SCHEDB();
    MMA0();
    SCHEDB();
    LGKM0();
    // window 63 (set1): mfma 63.
    MMA1();

    // epilogue: D row=(lane>>4)*4+j, col=lane&15 (shape-determined, i32 same
    // as f32); out = acc * sx[row] * sw[col]
    int m0 = mt * BM, n0 = nt * BN;
    int col0 = n0 + wn * 64 + (lane & 15);
    int row0 = m0 + wm * 128 + ((lane >> 4) << 2);
    float swv[4];
    #pragma unroll
    for (int ni = 0; ni < 4; ++ni) swv[ni] = scale[col0 + ni * 16];
    #pragma unroll
    for (int mi = 0; mi < 8; ++mi) {
        #pragma unroll
        for (int j = 0; j < 4; ++j) {
            int r = row0 + mi * 16 + j;
            float sr = sx[r];
            #pragma unroll
            for (int ni = 0; ni < 4; ++ni) {
                out[(size_t)r * N_TOTAL + (col0 + ni * 16)] = (float)acc[mi][ni][j] * sr * swv[ni];
            }
        }
    }
}

// ---------------- fallback ----------------

__global__ __launch_bounds__(256) void naive_kernel(const float* __restrict__ x, const int* __restrict__ w,
                                                    const float* __restrict__ scale, float* __restrict__ out) {
    int n = blockIdx.x * 256 + threadIdx.x;
    int m = blockIdx.y;
    const float* xr = x + (size_t)m * K_TOTAL;
    const int*   wr = w + (size_t)n * K_TOTAL;
    float acc = 0.f;
    for (int k = 0; k < K_TOTAL; k += 4) {
        float4 xv = *(const float4*)(xr + k);
        int4   wv = *(const int4*)(wr + k);
        acc += xv.x * (float)wv.x + xv.y * (float)wv.y + xv.z * (float)wv.z + xv.w * (float)wv.w;
    }
    out[(size_t)m * N_TOTAL + n] = acc * scale[n];
}

extern "C" void kernel_launch(void* const* d_in, const int* in_sizes, int n_in,
                              void* d_out, int out_size, void* d_ws, size_t ws_size,
                              hipStream_t stream) {
    const float* x     = (const float*)d_in[0];
    const int*   w     = (const int*)d_in[1];
    const float* scale = (const float*)d_in[2];
    float* out = (float*)d_out;

    const size_t xq_bytes = (size_t)M_TOTAL * K_TOTAL;       // 32MB
    const size_t wq_bytes = (size_t)N_TOTAL * K_TOTAL;       // 64MB
    const size_t sx_bytes = (size_t)M_TOTAL * 4;             // 32KB

    if (ws_size >= xq_bytes + wq_bytes + 2 * sx_bytes) {
        char*  xq   = (char*)d_ws;
        char*  wq   = (char*)d_ws + xq_bytes;
        float* sx   = (float*)((char*)d_ws + xq_bytes + wq_bytes);
        float* invx = sx + M_TOTAL;
        (void)hipFuncSetAttribute((const void*)gemm_kernel,
                                  hipFuncAttributeMaxDynamicSharedMemorySize, NBUF * BUF_S);
        rowmax_kernel<<<M_TOTAL / 4, 256, 0, stream>>>(x, sx, invx);
        cvt_x_pack<<<(M_TOTAL / 256) * (K_TOTAL / 16) , 256, 0, stream>>>(x, invx, xq);
        cvt_w_pack<<<(N_TOTAL / 256) * (K_TOTAL / 16), 256, 0, stream>>>(w, wq);
        gemm_kernel<<<(M_TOTAL / BM) * (N_TOTAL / BN), 512, NBUF * BUF_S, stream>>>(xq, wq, scale, sx, out);
    } else {
        dim3 g(N_TOTAL / 256, M_TOTAL);
        naive_kernel<<<g, 256, 0, stream>>>(x, w, scale, out);
    }
}

// Round 14
// 754.745 us; speedup vs baseline: 2.0903x; 1.0147x over previous
//
#include <hip/hip_runtime.h>
#include <hip/hip_bf16.h>
#include <stdint.h>

#define M_TOTAL 8192
#define K_TOTAL 4096
#define N_TOTAL 16384
#define BM 256
#define BN 256
#define KT 64                          // 64 K-tiles of 64 (i8: one MFMA eats K=64)
#define TILE_B 16384                   // bytes per 256-row block per K-tile (256 x 64 x 1B)
#define BUF_S 32768                    // LDS buffer: A 16KB + B 16KB
#define NBUF 4

typedef int i32x4 __attribute__((ext_vector_type(4)));

static __device__ __forceinline__ void async16(const void* g, void* l) {
    __builtin_amdgcn_global_load_lds((const __attribute__((address_space(1))) unsigned int*)g,
                                     (__attribute__((address_space(3))) unsigned int*)l,
                                     16, 0, 0);
}

// ---------------- scale + packing kernels ----------------
// Packed i8 layout per 256-row block (1MB): [kt 0..63][f 0..15][lane 0..63][16B]
// element (row, k): f=(row>>4)&15, lane=(row&15)|(((k>>4)&3)<<4), byte=k&15.
// Matches mfma_i32_16x16x64_i8 operand (verified by round-13 absmax 4.5).

__global__ __launch_bounds__(256) void rowmax_kernel(const float* __restrict__ x,
                                                     float* __restrict__ sx,
                                                     float* __restrict__ invx) {
    int row = blockIdx.x * 4 + (threadIdx.x >> 6);
    int lane = threadIdx.x & 63;
    const float4* p = reinterpret_cast<const float4*>(x + (size_t)row * K_TOTAL) + lane;
    float m = 0.f;
    #pragma unroll
    for (int i = 0; i < 16; ++i) {
        float4 v = p[i * 64];
        m = fmaxf(m, fmaxf(fmaxf(fabsf(v.x), fabsf(v.y)), fmaxf(fabsf(v.z), fabsf(v.w))));
    }
    #pragma unroll
    for (int off = 32; off; off >>= 1) m = fmaxf(m, __shfl_xor(m, off, 64));
    if (lane == 0) {
        m = fmaxf(m, 1e-20f);
        sx[row]   = m / 127.f;
        invx[row] = 127.f / m;
    }
}

__global__ __launch_bounds__(256) void cvt_x_pack(const float* __restrict__ x,
                                                  const float* __restrict__ invx,
                                                  char* __restrict__ xq) {
    size_t j = (size_t)blockIdx.x * 256 + threadIdx.x;   // 16 output bytes each
    int mt = (int)(j >> 16);           // 65536 threads per 256-row block
    int j2 = (int)(j & 65535);
    int kt = j2 >> 10;
    int f  = (j2 >> 6) & 15;
    int l  = j2 & 63;
    int r  = mt * 256 + f * 16 + (l & 15);
    int k0 = kt * 64 + ((l >> 4) << 4);
    float is = invx[r];
    const float4* s = reinterpret_cast<const float4*>(x + (size_t)r * K_TOTAL + k0);
    int q[16];
    #pragma unroll
    for (int v4 = 0; v4 < 4; ++v4) {
        float4 v = s[v4];
        q[v4 * 4 + 0] = (int)__builtin_rintf(v.x * is);
        q[v4 * 4 + 1] = (int)__builtin_rintf(v.y * is);
        q[v4 * 4 + 2] = (int)__builtin_rintf(v.z * is);
        q[v4 * 4 + 3] = (int)__builtin_rintf(v.w * is);
    }
    int4 d;
    d.x = (q[0]&0xff) | ((q[1]&0xff)<<8) | ((q[2]&0xff)<<16) | (q[3]<<24);
    d.y = (q[4]&0xff) | ((q[5]&0xff)<<8) | ((q[6]&0xff)<<16) | (q[7]<<24);
    d.z = (q[8]&0xff) | ((q[9]&0xff)<<8) | ((q[10]&0xff)<<16) | (q[11]<<24);
    d.w = (q[12]&0xff) | ((q[13]&0xff)<<8) | ((q[14]&0xff)<<16) | (q[15]<<24);
    *reinterpret_cast<int4*>(xq + j * 16) = d;
}

__global__ __launch_bounds__(256) void cvt_w_pack(const int* __restrict__ w,
                                                  char* __restrict__ wq) {
    size_t j = (size_t)blockIdx.x * 256 + threadIdx.x;
    int nt = (int)(j >> 16);
    int j2 = (int)(j & 65535);
    int kt = j2 >> 10;
    int f  = (j2 >> 6) & 15;
    int l  = j2 & 63;
    int r  = nt * 256 + f * 16 + (l & 15);
    int k0 = kt * 64 + ((l >> 4) << 4);
    const int4* s = reinterpret_cast<const int4*>(w + (size_t)r * K_TOTAL + k0);
    int4 v0 = s[0], v1 = s[1], v2 = s[2], v3 = s[3];
    int4 d;
    d.x = (v0.x&0xff) | ((v0.y&0xff)<<8) | ((v0.z&0xff)<<16) | (v0.w<<24);
    d.y = (v1.x&0xff) | ((v1.y&0xff)<<8) | ((v1.z&0xff)<<16) | (v1.w<<24);
    d.z = (v2.x&0xff) | ((v2.y&0xff)<<8) | ((v2.z&0xff)<<16) | (v2.w<<24);
    d.w = (v3.x&0xff) | ((v3.y&0xff)<<8) | ((v3.z&0xff)<<16) | (v3.w<<24);
    *reinterpret_cast<int4*>(wq + j * 16) = d;
}

// ---------------- GEMM: i8, NO end-of-window lgkm drain ----------------
// Window w (set s = w&1): STG(tile w+3 -> buf (w+3)&3); 12 ds_reads of tile
// w+1 -> set ~s; 32 mfma_i32_16x16x64_i8 on set s; vmcnt(4); barrier.
// KEY CHANGE vs round 13: no lgkmcnt(0) in the window. The reads issued at w
// retire lazily under window w+1's MFMA cluster via the compiler's counted
// lgkm waits (LDS returns FIFO; every frag is an MFMA operand, so the cluster
// retires all 12). Buf b read at w is overwritten at w+2 -- after w+1's
// barrier -- so the drain was pure serialization, not safety.
// vmcnt(4) (counted) still certifies tile w+2's stage before the barrier.

#define BAR()    { asm volatile("" ::: "memory"); __builtin_amdgcn_s_barrier(); asm volatile("" ::: "memory"); }
#define VMC4()   asm volatile("s_waitcnt vmcnt(4)" ::: "memory")
#define VMC0()   asm volatile("s_waitcnt vmcnt(0)" ::: "memory")
#define PRIO1()  __builtin_amdgcn_s_setprio(1)
#define PRIO0()  __builtin_amdgcn_s_setprio(0)
#define SCHEDB() __builtin_amdgcn_sched_barrier(0)

#define STG(ts, so) { \
    async16(aS + (size_t)(ts)*TILE_B + tid*16,        ldsc + (so) + tid*16); \
    async16(aS + (size_t)(ts)*TILE_B + 8192 + tid*16, ldsc + (so) + 8192 + tid*16); \
    async16(bS + (size_t)(ts)*TILE_B + tid*16,        ldsc + (so) + 16384 + tid*16); \
    async16(bS + (size_t)(ts)*TILE_B + 8192 + tid*16, ldsc + (so) + 24576 + tid*16); }

#define RDF0(bo) { \
    _Pragma("unroll") for (int ni = 0; ni < 4; ++ni) bfr0[ni] = *(const i32x4*)(bRd + (bo) + ni * 1024); \
    _Pragma("unroll") for (int mi = 0; mi < 8; ++mi) afr0[mi] = *(const i32x4*)(aRd + (bo) + mi * 1024); }

#define RDF1(bo) { \
    _Pragma("unroll") for (int ni = 0; ni < 4; ++ni) bfr1[ni] = *(const i32x4*)(bRd + (bo) + ni * 1024); \
    _Pragma("unroll") for (int mi = 0; mi < 8; ++mi) afr1[mi] = *(const i32x4*)(aRd + (bo) + mi * 1024); }

#define MMA0() { PRIO1(); \
    _Pragma("unroll") for (int mi = 0; mi < 8; ++mi) { _Pragma("unroll") \
        for (int ni = 0; ni < 4; ++ni) \
            acc[mi][ni] = __builtin_amdgcn_mfma_i32_16x16x64_i8(afr0[mi], bfr0[ni], acc[mi][ni], 0, 0, 0); } \
    PRIO0(); }

#define MMA1() { PRIO1(); \
    _Pragma("unroll") for (int mi = 0; mi < 8; ++mi) { _Pragma("unroll") \
        for (int ni = 0; ni < 4; ++ni) \
            acc[mi][ni] = __builtin_amdgcn_mfma_i32_16x16x64_i8(afr1[mi], bfr1[ni], acc[mi][ni], 0, 0, 0); } \
    PRIO0(); }

#define WIN(st, sb, rb, RDFx, MMAx) { \
    STG(st, sb); \
    RDFx(rb); \
    SCHEDB(); \
    MMAx(); \
    SCHEDB(); \
    VMC4(); BAR(); }

__global__ __launch_bounds__(512, 2) void gemm_kernel(const char* __restrict__ A,
                                                      const char* __restrict__ B,
                                                      const float* __restrict__ scale,
                                                      const float* __restrict__ sx,
                                                      float* __restrict__ out) {
    extern __shared__ char ldsc[];
    const int tid  = threadIdx.x;
    const int lane = tid & 63;
    const int wave = tid >> 6;
    const int wm = wave >> 2;          // 0..1
    const int wn = wave & 3;           // 0..3

    // XCD-aware bijective swizzle (2048 blocks, 8 XCDs, 256-block chunks);
    // mt fastest within chunk -> 32 co-resident blocks/XCD share one B-panel.
    int orig = blockIdx.x;
    int swzid = (orig & 7) * 256 + (orig >> 3);
    int mt = swzid & 31;
    int nt = swzid >> 5;

    const char* aS = A + (size_t)mt * (KT * TILE_B);
    const char* bS = B + (size_t)nt * (KT * TILE_B);

    // fragment read bases: stride-1 1KB wave reads (uniform base + lane*16)
    const char* aRd = ldsc + wm * 8192 + lane * 16;           // + bo + mi*1024
    const char* bRd = ldsc + 16384 + wn * 4096 + lane * 16;   // + bo + ni*1024

    i32x4 acc[8][4];
    #pragma unroll
    for (int mi = 0; mi < 8; ++mi)
        #pragma unroll
        for (int ni = 0; ni < 4; ++ni)
            acc[mi][ni] = (i32x4){0, 0, 0, 0};

    i32x4 afr0[8], bfr0[4], afr1[8], bfr1[4];

    // prologue: stage tiles 0,1,2 -> bufs 0,1,2; VMC4 drains stages 0,1;
    // barrier; read tile 0 -> set0 (consumed by window 0's MMA0 via
    // compiler-counted lgkm waits).
    STG(0, 0); STG(1, BUF_S); STG(2, 2 * BUF_S);
    VMC4();
    BAR();
    RDF0(0);

    // windows 0..59 (stage tiles 3..62), unroll x4 for static LDS offsets
    for (int T = 0; T < 60; T += 4) {
        WIN(T + 3, 3 * BUF_S, 1 * BUF_S, RDF1, MMA0);   // w=T:   mfma T,   rd T+1
        WIN(T + 4, 0,         2 * BUF_S, RDF0, MMA1);   // w=T+1: mfma T+1, rd T+2
        WIN(T + 5, 1 * BUF_S, 3 * BUF_S, RDF1, MMA0);   // w=T+2: mfma T+2, rd T+3
        WIN(T + 6, 2 * BUF_S, 0,         RDF0, MMA1);   // w=T+3: mfma T+3, rd T+4
    }
    // window 60 (set0): stage tile 63 -> buf3; rd tile 61 <- buf1; mfma 60.
    WIN(63, 3 * BUF_S, 1 * BUF_S, RDF1, MMA0);
    // window 61 (set1): rd tile 62 <- buf2; mfma 61; VMC0 certifies tile 63.
    RDF0(2 * BUF_S);
    SCHEDB();
    MMA1();
    SCHEDB();
    VMC0(); BAR();
    // window 62 (set0): rd tile 63 <- buf3; mfma 62.
    RDF1(3 * BUF_S);
    SCHEDB();
    MMA0();
    SCHEDB();
    // window 63 (set1): mfma 63 (compiler waits on set1's reads).
    MMA1();

    // epilogue: D row=(lane>>4)*4+j, col=lane&15 (shape-determined);
    // out = acc * sx[row] * sw[col]
    int m0 = mt * BM, n0 = nt * BN;
    int col0 = n0 + wn * 64 + (lane & 15);
    int row0 = m0 + wm * 128 + ((lane >> 4) << 2);
    float swv[4];
    #pragma unroll
    for (int ni = 0; ni < 4; ++ni) swv[ni] = scale[col0 + ni * 16];
    #pragma unroll
    for (int mi = 0; mi < 8; ++mi) {
        #pragma unroll
        for (int j = 0; j < 4; ++j) {
            int r = row0 + mi * 16 + j;
            float sr = sx[r];
            #pragma unroll
            for (int ni = 0; ni < 4; ++ni) {
                out[(size_t)r * N_TOTAL + (col0 + ni * 16)] = (float)acc[mi][ni][j] * sr * swv[ni];
            }
        }
    }
}

// ---------------- fallback ----------------

__global__ __launch_bounds__(256) void naive_kernel(const float* __restrict__ x, const int* __restrict__ w,
                                                    const float* __restrict__ scale, float* __restrict__ out) {
    int n = blockIdx.x * 256 + threadIdx.x;
    int m = blockIdx.y;
    const float* xr = x + (size_t)m * K_TOTAL;
    const int*   wr = w + (size_t)n * K_TOTAL;
    float acc = 0.f;
    for (int k = 0; k < K_TOTAL; k += 4) {
        float4 xv = *(const float4*)(xr + k);
        int4   wv = *(const int4*)(wr + k);
        acc += xv.x * (float)wv.x + xv.y * (float)wv.y + xv.z * (float)wv.z + xv.w * (float)wv.w;
    }
    out[(size_t)m * N_TOTAL + n] = acc * scale[n];
}

extern "C" void kernel_launch(void* const* d_in, const int* in_sizes, int n_in,
                              void* d_out, int out_size, void* d_ws, size_t ws_size,
                              hipStream_t stream) {
    const float* x     = (const float*)d_in[0];
    const int*   w     = (const int*)d_in[1];
    const float* scale = (const float*)d_in[2];
    float* out = (float*)d_out;

    const size_t xq_bytes = (size_t)M_TOTAL * K_TOTAL;       // 32MB
    const size_t wq_bytes = (size_t)N_TOTAL * K_TOTAL;       // 64MB
    const size_t sx_bytes = (size_t)M_TOTAL * 4;             // 32KB

    if (ws_size >= xq_bytes + wq_bytes + 2 * sx_bytes) {
        char*  xq   = (char*)d_ws;
        char*  wq   = (char*)d_ws + xq_bytes;
        float* sx   = (float*)((char*)d_ws + xq_bytes + wq_bytes);
        float* invx = sx + M_TOTAL;
        (void)hipFuncSetAttribute((const void*)gemm_kernel,
                                  hipFuncAttributeMaxDynamicSharedMemorySize, NBUF * BUF_S);
        rowmax_kernel<<<M_TOTAL / 4, 256, 0, stream>>>(x, sx, invx);
        cvt_x_pack<<<(M_TOTAL / 256) * (K_TOTAL / 16) , 256, 0, stream>>>(x, invx, xq);
        cvt_w_pack<<<(N_TOTAL / 256) * (K_TOTAL / 16), 256, 0, stream>>>(w, wq);
        gemm_kernel<<<(M_TOTAL / BM) * (N_TOTAL / BN), 512, NBUF * BUF_S, stream>>>(xq, wq, scale, sx, out);
    } else {
        dim3 g(N_TOTAL / 256, M_TOTAL);
        naive_kernel<<<g, 256, 0, stream>>>(x, w, scale, out);
    }
}